// Round 15
// baseline (64.761 us; speedup 1.0000x reference)
//
#include <hip/hip_runtime.h>

#define NN 8192
#define NE 262144
#define DIN 512
#define DOUT 256
#define LRELU_ALPHA 0.2f
#define RSLOT 96  // slots per row; Poisson(32) > 96 is +11 sigma => never
#define BM 64
#define BN 64
#define BK 64

using bf16x8 = __attribute__((ext_vector_type(8))) short;
using f32x4 = __attribute__((ext_vector_type(4))) float;

__device__ inline unsigned short bf16rne(float f) {
    unsigned u = __float_as_uint(f);
    return (unsigned short)((u + 0x7FFFu + ((u >> 16) & 1u)) >> 16);
}

// split 8 consecutive f32 into bf16 hi/lo fragments (truncation split)
__device__ inline void split8(const float4 a, const float4 b, bf16x8& hi, bf16x8& lo) {
    unsigned u0 = __float_as_uint(a.x), u1 = __float_as_uint(a.y);
    unsigned u2 = __float_as_uint(a.z), u3 = __float_as_uint(a.w);
    unsigned u4 = __float_as_uint(b.x), u5 = __float_as_uint(b.y);
    unsigned u6 = __float_as_uint(b.z), u7 = __float_as_uint(b.w);
    union { unsigned u[4]; bf16x8 v; } H_, L_;
    H_.u[0] = (u1 & 0xFFFF0000u) | (u0 >> 16);
    H_.u[1] = (u3 & 0xFFFF0000u) | (u2 >> 16);
    H_.u[2] = (u5 & 0xFFFF0000u) | (u4 >> 16);
    H_.u[3] = (u7 & 0xFFFF0000u) | (u6 >> 16);
    float l0 = a.x - __uint_as_float(u0 & 0xFFFF0000u);
    float l1 = a.y - __uint_as_float(u1 & 0xFFFF0000u);
    float l2 = a.z - __uint_as_float(u2 & 0xFFFF0000u);
    float l3 = a.w - __uint_as_float(u3 & 0xFFFF0000u);
    float l4 = b.x - __uint_as_float(u4 & 0xFFFF0000u);
    float l5 = b.y - __uint_as_float(u5 & 0xFFFF0000u);
    float l6 = b.z - __uint_as_float(u6 & 0xFFFF0000u);
    float l7 = b.w - __uint_as_float(u7 & 0xFFFF0000u);
    L_.u[0] = (__float_as_uint(l1) & 0xFFFF0000u) | (__float_as_uint(l0) >> 16);
    L_.u[1] = (__float_as_uint(l3) & 0xFFFF0000u) | (__float_as_uint(l2) >> 16);
    L_.u[2] = (__float_as_uint(l5) & 0xFFFF0000u) | (__float_as_uint(l4) >> 16);
    L_.u[3] = (__float_as_uint(l7) & 0xFFFF0000u) | (__float_as_uint(l6) >> 16);
    hi = H_.v;
    lo = L_.v;
}

// ---------------- K1: tiny zero-init (97 blocks; R14 showed memset node costs +5us) ----------------
__global__ __launch_bounds__(256) void zero_kernel(int* __restrict__ cnt,
                                                   float* __restrict__ Wh1,
                                                   float* __restrict__ Wh2,
                                                   float* __restrict__ Htot) {
    int idx = blockIdx.x * 256 + threadIdx.x;
    if (idx < NN) cnt[idx] = 0;
    else if (idx < 2 * NN) Wh1[idx - NN] = 0.f;
    else if (idx < 3 * NN) Wh2[idx - 2 * NN] = 0.f;
    else if (idx < 3 * NN + DOUT) Htot[idx - 3 * NN] = 0.f;
}

// swizzled LDS fragment read: row, kslot (16B slot within the 128B row), T2 XOR involution
__device__ inline bf16x8 frag_read(const short* lds, int row, int kslot) {
    return *(const bf16x8*)((const char*)lds + row * 128 + ((kslot ^ (row & 7)) << 4));
}

// ---------------- K2: MFMA GEMM: A dbuf LDS, B fragments built in-register from W + edges ----------------
// blocks [0,512): gemm, BM=BN=64, 4 waves 2x2 (32x32/wave); blocks [512,1536): edge slotting
__global__ __launch_bounds__(256) void gemm_edges_kernel(
    const float* __restrict__ X, const float* __restrict__ W,
    const float* __restrict__ av, const int* __restrict__ ei,
    int* __restrict__ cnt, int* __restrict__ csr_col,
    unsigned short* __restrict__ Hb, float* __restrict__ Wh1,
    float* __restrict__ Wh2, float* __restrict__ Htot) {
    if (blockIdx.x >= 512) {  // ---- edges path ----
        int e = (blockIdx.x - 512) * 256 + threadIdx.x;
        int r = ei[e];
        int c = ei[NE + e];
        int slot = atomicAdd(&cnt[r], 1);
        if (slot < RSLOT) csr_col[r * RSLOT + slot] = c;
        return;
    }
    // ---- gemm path ----
    __shared__ short Ah[2][BM * BK], Al[2][BM * BK];  // 4 x 8KB = 32KB (A only)
    int b = blockIdx.x;
    int m0 = (b & 127) * BM;
    int n0b = (b >> 7) * BN;
    int t = threadIdx.x;
    int w = t >> 6, lane = t & 63;
    int wm = w >> 1, wn = w & 1;
    int lr = lane & 15;          // A row / B col / D col within 16x16 tile
    int klg = lane >> 4;         // k-group 0..3
    int m0w = wm * 32;
    int n0w = wn * 32;

    // A staging indices: 512 slots (64 rows x 8 slots of 8 elems), 2 per thread
    int srow0 = t >> 3;   // rows srow0 and srow0+32
    int scs = t & 7;

    // B columns this lane owns (built in-register from W; bit-identical to Wf prep)
    const float* wc0 = W + (n0b + n0w + lr);
    const float* wc1 = wc0 + 16;

    f32x4 acc[2][2] = {};
    float4 px[2][2];

    // prologue: load + stage K-tile 0 into buffer 0
#pragma unroll
    for (int j = 0; j < 2; ++j) {
        int row = j * 32 + srow0;
        const float* xs = X + (size_t)(m0 + row) * DIN + scs * 8;
        px[j][0] = *(const float4*)xs;
        px[j][1] = *(const float4*)(xs + 4);
    }
#pragma unroll
    for (int j = 0; j < 2; ++j) {
        int row = j * 32 + srow0;
        int so = (scs ^ (row & 7)) << 4;
        bf16x8 hi, lo;
        split8(px[j][0], px[j][1], hi, lo);
        *(bf16x8*)((char*)Ah[0] + row * 128 + so) = hi;
        *(bf16x8*)((char*)Al[0] + row * 128 + so) = lo;
    }

    for (int i = 0; i < 8; ++i) {
        __syncthreads();  // buf[i&1] visible; prior reads of buf[(i+1)&1] complete

        // T14: issue next X tile's global loads; they fly under this tile's compute
        if (i < 7) {
            int kn = (i + 1) * BK;
#pragma unroll
            for (int j = 0; j < 2; ++j) {
                int row = j * 32 + srow0;
                const float* xs = X + (size_t)(m0 + row) * DIN + kn + scs * 8;
                px[j][0] = *(const float4*)xs;
                px[j][1] = *(const float4*)(xs + 4);
            }
        }

        const short* Ab = Ah[i & 1];
        const short* Alb = Al[i & 1];
#pragma unroll
        for (int ksub = 0; ksub < 2; ++ksub) {
            int ks = ksub * 4 + klg;
            // B fragments direct from W (krow = i*64 + ksub*32 + klg*8 + j, col = wave col)
            const float* p0 = wc0 + (size_t)(i * BK + ksub * 32 + klg * 8) * DOUT;
            const float* p1 = wc1 + (size_t)(i * BK + ksub * 32 + klg * 8) * DOUT;
            float4 wa0 = make_float4(p0[0], p0[DOUT], p0[2 * DOUT], p0[3 * DOUT]);
            float4 wb0 = make_float4(p0[4 * DOUT], p0[5 * DOUT], p0[6 * DOUT], p0[7 * DOUT]);
            float4 wa1 = make_float4(p1[0], p1[DOUT], p1[2 * DOUT], p1[3 * DOUT]);
            float4 wb1 = make_float4(p1[4 * DOUT], p1[5 * DOUT], p1[6 * DOUT], p1[7 * DOUT]);
            bf16x8 bh0, bl0, bh1, bl1;
            split8(wa0, wb0, bh0, bl0);
            split8(wa1, wb1, bh1, bl1);
            bf16x8 ah0 = frag_read(Ab, m0w + lr, ks);
            bf16x8 ah1 = frag_read(Ab, m0w + 16 + lr, ks);
            bf16x8 al0 = frag_read(Alb, m0w + lr, ks);
            bf16x8 al1 = frag_read(Alb, m0w + 16 + lr, ks);

            acc[0][0] = __builtin_amdgcn_mfma_f32_16x16x32_bf16(ah0, bh0, acc[0][0], 0, 0, 0);
            acc[0][1] = __builtin_amdgcn_mfma_f32_16x16x32_bf16(ah0, bh1, acc[0][1], 0, 0, 0);
            acc[1][0] = __builtin_amdgcn_mfma_f32_16x16x32_bf16(ah1, bh0, acc[1][0], 0, 0, 0);
            acc[1][1] = __builtin_amdgcn_mfma_f32_16x16x32_bf16(ah1, bh1, acc[1][1], 0, 0, 0);
            acc[0][0] = __builtin_amdgcn_mfma_f32_16x16x32_bf16(ah0, bl0, acc[0][0], 0, 0, 0);
            acc[0][1] = __builtin_amdgcn_mfma_f32_16x16x32_bf16(ah0, bl1, acc[0][1], 0, 0, 0);
            acc[1][0] = __builtin_amdgcn_mfma_f32_16x16x32_bf16(ah1, bl0, acc[1][0], 0, 0, 0);
            acc[1][1] = __builtin_amdgcn_mfma_f32_16x16x32_bf16(ah1, bl1, acc[1][1], 0, 0, 0);
            acc[0][0] = __builtin_amdgcn_mfma_f32_16x16x32_bf16(al0, bh0, acc[0][0], 0, 0, 0);
            acc[0][1] = __builtin_amdgcn_mfma_f32_16x16x32_bf16(al0, bh1, acc[0][1], 0, 0, 0);
            acc[1][0] = __builtin_amdgcn_mfma_f32_16x16x32_bf16(al1, bh0, acc[1][0], 0, 0, 0);
            acc[1][1] = __builtin_amdgcn_mfma_f32_16x16x32_bf16(al1, bh1, acc[1][1], 0, 0, 0);
        }

        // stage next tile into the other buffer (its readers finished before this iter's barrier)
        if (i < 7) {
#pragma unroll
            for (int j = 0; j < 2; ++j) {
                int row = j * 32 + srow0;
                int so = (scs ^ (row & 7)) << 4;
                bf16x8 hi, lo;
                split8(px[j][0], px[j][1], hi, lo);
                *(bf16x8*)((char*)Ah[(i + 1) & 1] + row * 128 + so) = hi;
                *(bf16x8*)((char*)Al[(i + 1) & 1] + row * 128 + so) = lo;
            }
        }
    }

    // store H tile as bf16 (RNE)
    int orow = (lane >> 4) * 4;
#pragma unroll
    for (int mt = 0; mt < 2; ++mt)
#pragma unroll
        for (int nt = 0; nt < 2; ++nt)
#pragma unroll
            for (int r = 0; r < 4; ++r)
                Hb[(size_t)(m0 + m0w + mt * 16 + orow + r) * DOUT + n0b + n0w + nt * 16 + lr] =
                    bf16rne(acc[mt][nt][r]);

    // fused epilogue: Wh1/Wh2 partial row-dots over this wave's 32 cols (f32 exact)
    float a1v0 = av[n0b + n0w + lr];
    float a1v1 = av[n0b + n0w + 16 + lr];
    float a2v0 = av[DOUT + n0b + n0w + lr];
    float a2v1 = av[DOUT + n0b + n0w + 16 + lr];
#pragma unroll
    for (int mt = 0; mt < 2; ++mt)
#pragma unroll
        for (int r = 0; r < 4; ++r) {
            float d1 = acc[mt][0][r] * a1v0 + acc[mt][1][r] * a1v1;
            float d2 = acc[mt][0][r] * a2v0 + acc[mt][1][r] * a2v1;
#pragma unroll
            for (int ofs = 1; ofs < 16; ofs <<= 1) {
                d1 += __shfl_xor(d1, ofs);
                d2 += __shfl_xor(d2, ofs);
            }
            if (lr == 0) {
                int row = m0 + m0w + mt * 16 + orow + r;
                atomicAdd(&Wh1[row], d1);
                atomicAdd(&Wh2[row], d2);
            }
        }

    // fused epilogue: Htot partial col-sums over this wave's 32 rows (f32 exact)
#pragma unroll
    for (int nt = 0; nt < 2; ++nt) {
        float s = 0.f;
#pragma unroll
        for (int mt = 0; mt < 2; ++mt)
#pragma unroll
            for (int r = 0; r < 4; ++r) s += acc[mt][nt][r];
        s += __shfl_xor(s, 16);
        s += __shfl_xor(s, 32);
        if (lane < 16) atomicAdd(&Htot[n0b + n0w + nt * 16 + lane], s);
    }
}

// ---------------- K3: per-row (one WAVE per row): dedup, analytic softmax, aggregate ----------------
__global__ __launch_bounds__(256) void row_kernel(
    const unsigned short* __restrict__ Hb, const float* __restrict__ Wh1,
    const float* __restrict__ Wh2, const float* __restrict__ Htot,
    const int* __restrict__ cnt, const int* __restrict__ csr_col,
    const float* __restrict__ bias, float* __restrict__ out) {
    __shared__ int scols[4][RSLOT];
    __shared__ float svv[4][RSLOT];
    int tid = threadIdx.x;
    int w = tid >> 6, lane = tid & 63;
    int i = blockIdx.x * 4 + w;
    int n = cnt[i];
    n = n < RSLOT ? n : RSLOT;
    int* colp = scols[w];
    float* vvp = svv[w];
    for (int t = lane; t < n; t += 64) colp[t] = csr_col[i * RSLOT + t];
    __syncthreads();

    const float NEG_INF = -__builtin_inff();
    float wh1 = Wh1[i];
    float localD = 0.f;
    float localm = 0.f;  // baseline 0 from the NN-D zero entries
    for (int t = lane; t < n; t += 64) {
        int c = colp[t];
        int k = 0;
        bool first = true;
        for (int q = 0; q < n; ++q) {
            int cq = colp[q];
            k += (cq == c);
            if (cq == c && q < t) first = false;
        }
        float v;
        if (first) {
            float s = wh1 + Wh2[c];
            s = s > 0.f ? s : LRELU_ALPHA * s;
            v = (float)k * s;  // duplicates sum to k * e_ij
            localD += 1.f;
            localm = fmaxf(localm, v);
        } else {
            v = NEG_INF;
        }
        vvp[t] = v;
    }

    float m = localm, D = localD;
#pragma unroll
    for (int ofs = 32; ofs > 0; ofs >>= 1) {
        m = fmaxf(m, __shfl_xor(m, ofs));
        D += __shfl_xor(D, ofs);
    }

    float em = expf(-m);
    float localZ = 0.f;
    for (int t = lane; t < n; t += 64) {
        float v = vvp[t];
        if (v != NEG_INF) localZ += expf(v - m);
    }
    float Z = localZ;
#pragma unroll
    for (int ofs = 32; ofs > 0; ofs >>= 1) Z += __shfl_xor(Z, ofs);
    Z += ((float)NN - D) * em;
    float invZ = 1.f / Z;

    for (int t = lane; t < n; t += 64) {
        float v = vvp[t];
        vvp[t] = (v != NEG_INF) ? (expf(v - m) - em) * invZ : 0.f;
    }
    __syncthreads();

    // aggregation: 8 independent accumulators, bf16x4 (8B/lane) coalesced gathers
    float4 a4[8];
#pragma unroll
    for (int j = 0; j < 8; ++j) a4[j] = make_float4(0.f, 0.f, 0.f, 0.f);
    int t = 0;
    for (; t + 8 <= n; t += 8) {
#pragma unroll
        for (int j = 0; j < 8; ++j) {
            float wc = vvp[t + j];
            int cc = colp[t + j];
            const ushort4 hv = *(const ushort4*)(Hb + (size_t)cc * DOUT + lane * 4);
            a4[j].x = fmaf(wc, __uint_as_float((unsigned)hv.x << 16), a4[j].x);
            a4[j].y = fmaf(wc, __uint_as_float((unsigned)hv.y << 16), a4[j].y);
            a4[j].z = fmaf(wc, __uint_as_float((unsigned)hv.z << 16), a4[j].z);
            a4[j].w = fmaf(wc, __uint_as_float((unsigned)hv.w << 16), a4[j].w);
        }
    }
    for (; t < n; ++t) {
        float wc = vvp[t];
        int cc = colp[t];
        const ushort4 hv = *(const ushort4*)(Hb + (size_t)cc * DOUT + lane * 4);
        a4[0].x = fmaf(wc, __uint_as_float((unsigned)hv.x << 16), a4[0].x);
        a4[0].y = fmaf(wc, __uint_as_float((unsigned)hv.y << 16), a4[0].y);
        a4[0].z = fmaf(wc, __uint_as_float((unsigned)hv.z << 16), a4[0].z);
        a4[0].w = fmaf(wc, __uint_as_float((unsigned)hv.w << 16), a4[0].w);
    }
#pragma unroll
    for (int j = 1; j < 8; ++j) {
        a4[0].x += a4[j].x; a4[0].y += a4[j].y; a4[0].z += a4[j].z; a4[0].w += a4[j].w;
    }
    float bc = em * invZ;
    const float4 ht = *(const float4*)(Htot + lane * 4);
    float4 acc = a4[0];
    acc.x = fmaf(bc, ht.x, acc.x);
    acc.y = fmaf(bc, ht.y, acc.y);
    acc.z = fmaf(bc, ht.z, acc.z);
    acc.w = fmaf(bc, ht.w, acc.w);

    float4 val;
    val.x = acc.x > 0.f ? acc.x : LRELU_ALPHA * acc.x;
    val.y = acc.y > 0.f ? acc.y : LRELU_ALPHA * acc.y;
    val.z = acc.z > 0.f ? acc.z : LRELU_ALPHA * acc.z;
    val.w = acc.w > 0.f ? acc.w : LRELU_ALPHA * acc.w;

    float ssq = val.x * val.x + val.y * val.y + val.z * val.z + val.w * val.w;
#pragma unroll
    for (int ofs = 32; ofs > 0; ofs >>= 1) ssq += __shfl_xor(ssq, ofs);
    float inv_nrm = 1.f / fmaxf(sqrtf(ssq), 1e-12f);

    const float4 b4 = *(const float4*)(bias + lane * 4);
    float4 o;
    o.x = fmaf(val.x, inv_nrm, b4.x);
    o.y = fmaf(val.y, inv_nrm, b4.y);
    o.z = fmaf(val.z, inv_nrm, b4.z);
    o.w = fmaf(val.w, inv_nrm, b4.w);
    *(float4*)(out + (size_t)i * DOUT + lane * 4) = o;
}

extern "C" void kernel_launch(void* const* d_in, const int* in_sizes, int n_in,
                              void* d_out, int out_size, void* d_ws, size_t ws_size,
                              hipStream_t stream) {
    const float* x = (const float*)d_in[0];
    const int* ei = (const int*)d_in[1];   // int64 in reference -> int32 here
    const float* w = (const float*)d_in[2];
    const float* a = (const float*)d_in[3];
    const float* bias = (const float*)d_in[4];
    float* out = (float*)d_out;

    // workspace layout (~7.2 MB)
    float* Wh1 = (float*)d_ws;                       // NN
    float* Wh2 = Wh1 + NN;                           // NN
    float* Htot = Wh2 + NN;                          // DOUT
    int* cnt = (int*)(Htot + DOUT);                  // NN
    int* csr_col = cnt + NN;                         // NN*RSLOT
    unsigned short* Hb = (unsigned short*)(csr_col + (size_t)NN * RSLOT);  // NN*DOUT bf16

    zero_kernel<<<(3 * NN + DOUT + 255) / 256, 256, 0, stream>>>(cnt, Wh1, Wh2, Htot);
    gemm_edges_kernel<<<512 + NE / 256, 256, 0, stream>>>(
        x, w, a, ei, cnt, csr_col, Hb, Wh1, Wh2, Htot);
    row_kernel<<<NN / 4, 256, 0, stream>>>(Hb, Wh1, Wh2, Htot, cnt, csr_col, bias, out);
}

// Round 16
// 57.826 us; speedup vs baseline: 1.1199x; 1.1199x over previous
//
#include <hip/hip_runtime.h>

#define NN 8192
#define NE 262144
#define DIN 512
#define DOUT 256
#define LRELU_ALPHA 0.2f
#define RSLOT 96  // slots per row; Poisson(32) > 96 is +11 sigma => never
#define BM 64
#define BN 64
#define BK 64

using bf16x8 = __attribute__((ext_vector_type(8))) short;
using f32x4 = __attribute__((ext_vector_type(4))) float;

__device__ inline unsigned short bf16rne(float f) {
    unsigned u = __float_as_uint(f);
    return (unsigned short)((u + 0x7FFFu + ((u >> 16) & 1u)) >> 16);
}

// split 8 consecutive f32 into bf16 hi/lo fragments (truncation split)
__device__ inline void split8(const float4 a, const float4 b, bf16x8& hi, bf16x8& lo) {
    unsigned u0 = __float_as_uint(a.x), u1 = __float_as_uint(a.y);
    unsigned u2 = __float_as_uint(a.z), u3 = __float_as_uint(a.w);
    unsigned u4 = __float_as_uint(b.x), u5 = __float_as_uint(b.y);
    unsigned u6 = __float_as_uint(b.z), u7 = __float_as_uint(b.w);
    union { unsigned u[4]; bf16x8 v; } H_, L_;
    H_.u[0] = (u1 & 0xFFFF0000u) | (u0 >> 16);
    H_.u[1] = (u3 & 0xFFFF0000u) | (u2 >> 16);
    H_.u[2] = (u5 & 0xFFFF0000u) | (u4 >> 16);
    H_.u[3] = (u7 & 0xFFFF0000u) | (u6 >> 16);
    float l0 = a.x - __uint_as_float(u0 & 0xFFFF0000u);
    float l1 = a.y - __uint_as_float(u1 & 0xFFFF0000u);
    float l2 = a.z - __uint_as_float(u2 & 0xFFFF0000u);
    float l3 = a.w - __uint_as_float(u3 & 0xFFFF0000u);
    float l4 = b.x - __uint_as_float(u4 & 0xFFFF0000u);
    float l5 = b.y - __uint_as_float(u5 & 0xFFFF0000u);
    float l6 = b.z - __uint_as_float(u6 & 0xFFFF0000u);
    float l7 = b.w - __uint_as_float(u7 & 0xFFFF0000u);
    L_.u[0] = (__float_as_uint(l1) & 0xFFFF0000u) | (__float_as_uint(l0) >> 16);
    L_.u[1] = (__float_as_uint(l3) & 0xFFFF0000u) | (__float_as_uint(l2) >> 16);
    L_.u[2] = (__float_as_uint(l5) & 0xFFFF0000u) | (__float_as_uint(l4) >> 16);
    L_.u[3] = (__float_as_uint(l7) & 0xFFFF0000u) | (__float_as_uint(l6) >> 16);
    hi = H_.v;
    lo = L_.v;
}

// ---------------- K1: prep = W-split (transposed) + zero-init (354 blocks, tiny) ----------------
__global__ __launch_bounds__(256) void prep_kernel(const float* __restrict__ W,
                                                   short* __restrict__ Wthi,
                                                   short* __restrict__ Wtlo,
                                                   int* __restrict__ cnt,
                                                   float* __restrict__ Wh1,
                                                   float* __restrict__ Wh2,
                                                   float* __restrict__ Htot) {
    int b = blockIdx.x;
    int t = threadIdx.x;
    if (b < DOUT) {
        int n = b;
        float w0 = W[(size_t)(2 * t) * DOUT + n];
        float w1 = W[(size_t)(2 * t + 1) * DOUT + n];
        unsigned u0 = __float_as_uint(w0), u1 = __float_as_uint(w1);
        unsigned hp = (u1 & 0xFFFF0000u) | (u0 >> 16);
        float l0 = w0 - __uint_as_float(u0 & 0xFFFF0000u);
        float l1 = w1 - __uint_as_float(u1 & 0xFFFF0000u);
        unsigned lp = (__float_as_uint(l1) & 0xFFFF0000u) | (__float_as_uint(l0) >> 16);
        ((unsigned*)Wthi)[n * (DIN / 2) + t] = hp;
        ((unsigned*)Wtlo)[n * (DIN / 2) + t] = lp;
    } else {
        int idx = (b - DOUT) * 256 + t;
        if (idx < NN) cnt[idx] = 0;
        else if (idx < 2 * NN) Wh1[idx - NN] = 0.f;
        else if (idx < 3 * NN) Wh2[idx - 2 * NN] = 0.f;
        else if (idx < 3 * NN + DOUT) Htot[idx - 3 * NN] = 0.f;
    }
}

// swizzled LDS fragment read: row, kslot (16B slot within the 128B row), T2 XOR involution
__device__ inline bf16x8 frag_read(const short* lds, int row, int kslot) {
    return *(const bf16x8*)((const char*)lds + row * 128 + ((kslot ^ (row & 7)) << 4));
}

// ---------------- K2: LDS-staged MFMA GEMM, inline X-split, T14 pipelined staging + edges ----------------
// blocks [0,512): gemm, BM=BN=64, 4 waves 2x2 (32x32/wave); blocks [512,1536): edge slotting
__global__ __launch_bounds__(256) void gemm_edges_kernel(
    const float* __restrict__ X,
    const short* __restrict__ Wthi, const short* __restrict__ Wtlo,
    const float* __restrict__ av, const int* __restrict__ ei,
    int* __restrict__ cnt, int* __restrict__ csr_col,
    unsigned short* __restrict__ Hb, float* __restrict__ Wh1,
    float* __restrict__ Wh2, float* __restrict__ Htot) {
    if (blockIdx.x >= 512) {  // ---- edges path ----
        int e = (blockIdx.x - 512) * 256 + threadIdx.x;
        int r = ei[e];
        int c = ei[NE + e];
        int slot = atomicAdd(&cnt[r], 1);
        if (slot < RSLOT) csr_col[r * RSLOT + slot] = c;
        return;
    }
    // ---- gemm path ----
    __shared__ short Ah[BM * BK], Al[BM * BK], Bh[BN * BK], Bl[BN * BK];  // 4 x 8KB
    int b = blockIdx.x;
    int m0 = (b & 127) * BM;
    int n0b = (b >> 7) * BN;
    int t = threadIdx.x;
    int w = t >> 6, lane = t & 63;
    int wm = w >> 1, wn = w & 1;
    int lr = lane & 15;          // A row / B col / D col within 16x16 tile
    int klg = lane >> 4;         // k-group 0..3
    int m0w = wm * 32;
    int n0w = wn * 32;

    // staging indices: 512 slots (64 rows x 8 slots of 8 elems), 2 per thread
    int srow0 = t >> 3;   // rows srow0 and srow0+32
    int scs = t & 7;

    f32x4 acc[2][2] = {};
    float4 px[2][2];     // prefetched X f32 (8 floats per j)
    bf16x8 pbh[2], pbl[2];

    // prologue: load K-tile 0
#pragma unroll
    for (int j = 0; j < 2; ++j) {
        int row = j * 32 + srow0;
        const float* xs = X + (size_t)(m0 + row) * DIN + scs * 8;
        px[j][0] = *(const float4*)xs;
        px[j][1] = *(const float4*)(xs + 4);
        pbh[j] = *(const bf16x8*)(Wthi + (size_t)(n0b + row) * DIN + scs * 8);
        pbl[j] = *(const bf16x8*)(Wtlo + (size_t)(n0b + row) * DIN + scs * 8);
    }

    for (int k0 = 0; k0 < DIN; k0 += BK) {
        // stage current regs -> LDS (swizzled)
#pragma unroll
        for (int j = 0; j < 2; ++j) {
            int row = j * 32 + srow0;
            int so = ((scs ^ (row & 7)) << 4);
            bf16x8 hi, lo;
            split8(px[j][0], px[j][1], hi, lo);
            *(bf16x8*)((char*)Ah + row * 128 + so) = hi;
            *(bf16x8*)((char*)Al + row * 128 + so) = lo;
            *(bf16x8*)((char*)Bh + row * 128 + so) = pbh[j];
            *(bf16x8*)((char*)Bl + row * 128 + so) = pbl[j];
        }
        __syncthreads();

        // T14: issue next tile's global loads now; they fly under the MFMA phase
        int kn = k0 + BK;
        if (kn < DIN) {
#pragma unroll
            for (int j = 0; j < 2; ++j) {
                int row = j * 32 + srow0;
                const float* xs = X + (size_t)(m0 + row) * DIN + kn + scs * 8;
                px[j][0] = *(const float4*)xs;
                px[j][1] = *(const float4*)(xs + 4);
                pbh[j] = *(const bf16x8*)(Wthi + (size_t)(n0b + row) * DIN + kn + scs * 8);
                pbl[j] = *(const bf16x8*)(Wtlo + (size_t)(n0b + row) * DIN + kn + scs * 8);
            }
        }

#pragma unroll
        for (int ksub = 0; ksub < 2; ++ksub) {
            int ks = ksub * 4 + klg;
            bf16x8 ah0 = frag_read(Ah, m0w + lr, ks);
            bf16x8 ah1 = frag_read(Ah, m0w + 16 + lr, ks);
            bf16x8 al0 = frag_read(Al, m0w + lr, ks);
            bf16x8 al1 = frag_read(Al, m0w + 16 + lr, ks);
            bf16x8 bh0 = frag_read(Bh, n0w + lr, ks);
            bf16x8 bh1 = frag_read(Bh, n0w + 16 + lr, ks);
            bf16x8 bl0 = frag_read(Bl, n0w + lr, ks);
            bf16x8 bl1 = frag_read(Bl, n0w + 16 + lr, ks);

            acc[0][0] = __builtin_amdgcn_mfma_f32_16x16x32_bf16(ah0, bh0, acc[0][0], 0, 0, 0);
            acc[0][1] = __builtin_amdgcn_mfma_f32_16x16x32_bf16(ah0, bh1, acc[0][1], 0, 0, 0);
            acc[1][0] = __builtin_amdgcn_mfma_f32_16x16x32_bf16(ah1, bh0, acc[1][0], 0, 0, 0);
            acc[1][1] = __builtin_amdgcn_mfma_f32_16x16x32_bf16(ah1, bh1, acc[1][1], 0, 0, 0);
            acc[0][0] = __builtin_amdgcn_mfma_f32_16x16x32_bf16(ah0, bl0, acc[0][0], 0, 0, 0);
            acc[0][1] = __builtin_amdgcn_mfma_f32_16x16x32_bf16(ah0, bl1, acc[0][1], 0, 0, 0);
            acc[1][0] = __builtin_amdgcn_mfma_f32_16x16x32_bf16(ah1, bl0, acc[1][0], 0, 0, 0);
            acc[1][1] = __builtin_amdgcn_mfma_f32_16x16x32_bf16(ah1, bl1, acc[1][1], 0, 0, 0);
            acc[0][0] = __builtin_amdgcn_mfma_f32_16x16x32_bf16(al0, bh0, acc[0][0], 0, 0, 0);
            acc[0][1] = __builtin_amdgcn_mfma_f32_16x16x32_bf16(al0, bh1, acc[0][1], 0, 0, 0);
            acc[1][0] = __builtin_amdgcn_mfma_f32_16x16x32_bf16(al1, bh0, acc[1][0], 0, 0, 0);
            acc[1][1] = __builtin_amdgcn_mfma_f32_16x16x32_bf16(al1, bh1, acc[1][1], 0, 0, 0);
        }
        __syncthreads();
    }

    // store H tile as bf16 (RNE)
    int orow = (lane >> 4) * 4;
#pragma unroll
    for (int mt = 0; mt < 2; ++mt)
#pragma unroll
        for (int nt = 0; nt < 2; ++nt)
#pragma unroll
            for (int r = 0; r < 4; ++r)
                Hb[(size_t)(m0 + m0w + mt * 16 + orow + r) * DOUT + n0b + n0w + nt * 16 + lr] =
                    bf16rne(acc[mt][nt][r]);

    // fused epilogue: Wh1/Wh2 partial row-dots over this wave's 32 cols (f32 exact)
    float a1v0 = av[n0b + n0w + lr];
    float a1v1 = av[n0b + n0w + 16 + lr];
    float a2v0 = av[DOUT + n0b + n0w + lr];
    float a2v1 = av[DOUT + n0b + n0w + 16 + lr];
#pragma unroll
    for (int mt = 0; mt < 2; ++mt)
#pragma unroll
        for (int r = 0; r < 4; ++r) {
            float d1 = acc[mt][0][r] * a1v0 + acc[mt][1][r] * a1v1;
            float d2 = acc[mt][0][r] * a2v0 + acc[mt][1][r] * a2v1;
#pragma unroll
            for (int ofs = 1; ofs < 16; ofs <<= 1) {
                d1 += __shfl_xor(d1, ofs);
                d2 += __shfl_xor(d2, ofs);
            }
            if (lr == 0) {
                int row = m0 + m0w + mt * 16 + orow + r;
                atomicAdd(&Wh1[row], d1);
                atomicAdd(&Wh2[row], d2);
            }
        }

    // fused epilogue: Htot partial col-sums over this wave's 32 rows (f32 exact)
#pragma unroll
    for (int nt = 0; nt < 2; ++nt) {
        float s = 0.f;
#pragma unroll
        for (int mt = 0; mt < 2; ++mt)
#pragma unroll
            for (int r = 0; r < 4; ++r) s += acc[mt][nt][r];
        s += __shfl_xor(s, 16);
        s += __shfl_xor(s, 32);
        if (lane < 16) atomicAdd(&Htot[n0b + n0w + nt * 16 + lane], s);
    }
}

// ---------------- K3: per-row (one WAVE per row): dedup, analytic softmax, aggregate ----------------
__global__ __launch_bounds__(256) void row_kernel(
    const unsigned short* __restrict__ Hb, const float* __restrict__ Wh1,
    const float* __restrict__ Wh2, const float* __restrict__ Htot,
    const int* __restrict__ cnt, const int* __restrict__ csr_col,
    const float* __restrict__ bias, float* __restrict__ out) {
    __shared__ int scols[4][RSLOT];
    __shared__ float svv[4][RSLOT];
    int tid = threadIdx.x;
    int w = tid >> 6, lane = tid & 63;
    int i = blockIdx.x * 4 + w;
    int n = cnt[i];
    n = n < RSLOT ? n : RSLOT;
    int* colp = scols[w];
    float* vvp = svv[w];
    for (int t = lane; t < n; t += 64) colp[t] = csr_col[i * RSLOT + t];
    __syncthreads();

    const float NEG_INF = -__builtin_inff();
    float wh1 = Wh1[i];
    float localD = 0.f;
    float localm = 0.f;  // baseline 0 from the NN-D zero entries
    for (int t = lane; t < n; t += 64) {
        int c = colp[t];
        int k = 0;
        bool first = true;
        for (int q = 0; q < n; ++q) {
            int cq = colp[q];
            k += (cq == c);
            if (cq == c && q < t) first = false;
        }
        float v;
        if (first) {
            float s = wh1 + Wh2[c];
            s = s > 0.f ? s : LRELU_ALPHA * s;
            v = (float)k * s;  // duplicates sum to k * e_ij
            localD += 1.f;
            localm = fmaxf(localm, v);
        } else {
            v = NEG_INF;
        }
        vvp[t] = v;
    }

    float m = localm, D = localD;
#pragma unroll
    for (int ofs = 32; ofs > 0; ofs >>= 1) {
        m = fmaxf(m, __shfl_xor(m, ofs));
        D += __shfl_xor(D, ofs);
    }

    float em = expf(-m);
    float localZ = 0.f;
    for (int t = lane; t < n; t += 64) {
        float v = vvp[t];
        if (v != NEG_INF) localZ += expf(v - m);
    }
    float Z = localZ;
#pragma unroll
    for (int ofs = 32; ofs > 0; ofs >>= 1) Z += __shfl_xor(Z, ofs);
    Z += ((float)NN - D) * em;
    float invZ = 1.f / Z;

    for (int t = lane; t < n; t += 64) {
        float v = vvp[t];
        vvp[t] = (v != NEG_INF) ? (expf(v - m) - em) * invZ : 0.f;
    }
    __syncthreads();

    // aggregation: 8 independent accumulators, bf16x4 (8B/lane) coalesced gathers
    float4 a4[8];
#pragma unroll
    for (int j = 0; j < 8; ++j) a4[j] = make_float4(0.f, 0.f, 0.f, 0.f);
    int t = 0;
    for (; t + 8 <= n; t += 8) {
#pragma unroll
        for (int j = 0; j < 8; ++j) {
            float wc = vvp[t + j];
            int cc = colp[t + j];
            const ushort4 hv = *(const ushort4*)(Hb + (size_t)cc * DOUT + lane * 4);
            a4[j].x = fmaf(wc, __uint_as_float((unsigned)hv.x << 16), a4[j].x);
            a4[j].y = fmaf(wc, __uint_as_float((unsigned)hv.y << 16), a4[j].y);
            a4[j].z = fmaf(wc, __uint_as_float((unsigned)hv.z << 16), a4[j].z);
            a4[j].w = fmaf(wc, __uint_as_float((unsigned)hv.w << 16), a4[j].w);
        }
    }
    for (; t < n; ++t) {
        float wc = vvp[t];
        int cc = colp[t];
        const ushort4 hv = *(const ushort4*)(Hb + (size_t)cc * DOUT + lane * 4);
        a4[0].x = fmaf(wc, __uint_as_float((unsigned)hv.x << 16), a4[0].x);
        a4[0].y = fmaf(wc, __uint_as_float((unsigned)hv.y << 16), a4[0].y);
        a4[0].z = fmaf(wc, __uint_as_float((unsigned)hv.z << 16), a4[0].z);
        a4[0].w = fmaf(wc, __uint_as_float((unsigned)hv.w << 16), a4[0].w);
    }
#pragma unroll
    for (int j = 1; j < 8; ++j) {
        a4[0].x += a4[j].x; a4[0].y += a4[j].y; a4[0].z += a4[j].z; a4[0].w += a4[j].w;
    }
    float bc = em * invZ;
    const float4 ht = *(const float4*)(Htot + lane * 4);
    float4 acc = a4[0];
    acc.x = fmaf(bc, ht.x, acc.x);
    acc.y = fmaf(bc, ht.y, acc.y);
    acc.z = fmaf(bc, ht.z, acc.z);
    acc.w = fmaf(bc, ht.w, acc.w);

    float4 val;
    val.x = acc.x > 0.f ? acc.x : LRELU_ALPHA * acc.x;
    val.y = acc.y > 0.f ? acc.y : LRELU_ALPHA * acc.y;
    val.z = acc.z > 0.f ? acc.z : LRELU_ALPHA * acc.z;
    val.w = acc.w > 0.f ? acc.w : LRELU_ALPHA * acc.w;

    float ssq = val.x * val.x + val.y * val.y + val.z * val.z + val.w * val.w;
#pragma unroll
    for (int ofs = 32; ofs > 0; ofs >>= 1) ssq += __shfl_xor(ssq, ofs);
    float inv_nrm = 1.f / fmaxf(sqrtf(ssq), 1e-12f);

    const float4 b4 = *(const float4*)(bias + lane * 4);
    float4 o;
    o.x = fmaf(val.x, inv_nrm, b4.x);
    o.y = fmaf(val.y, inv_nrm, b4.y);
    o.z = fmaf(val.z, inv_nrm, b4.z);
    o.w = fmaf(val.w, inv_nrm, b4.w);
    *(float4*)(out + (size_t)i * DOUT + lane * 4) = o;
}

extern "C" void kernel_launch(void* const* d_in, const int* in_sizes, int n_in,
                              void* d_out, int out_size, void* d_ws, size_t ws_size,
                              hipStream_t stream) {
    const float* x = (const float*)d_in[0];
    const int* ei = (const int*)d_in[1];   // int64 in reference -> int32 here
    const float* w = (const float*)d_in[2];
    const float* a = (const float*)d_in[3];
    const float* bias = (const float*)d_in[4];
    float* out = (float*)d_out;

    // workspace layout (~7.7 MB)
    float* Wh1 = (float*)d_ws;                       // NN
    float* Wh2 = Wh1 + NN;                           // NN
    float* Htot = Wh2 + NN;                          // DOUT
    int* cnt = (int*)(Htot + DOUT);                  // NN
    int* csr_col = cnt + NN;                         // NN*RSLOT
    unsigned short* Hb = (unsigned short*)(csr_col + (size_t)NN * RSLOT);  // NN*DOUT bf16
    short* wthi = (short*)(Hb + (size_t)NN * DOUT);  // DOUT*DIN bf16
    short* wtlo = wthi + (size_t)DOUT * DIN;         // DOUT*DIN bf16

    prep_kernel<<<DOUT + 98, 256, 0, stream>>>(w, wthi, wtlo, cnt, Wh1, Wh2, Htot);
    gemm_edges_kernel<<<512 + NE / 256, 256, 0, stream>>>(
        x, wthi, wtlo, a, ei, cnt, csr_col, Hb, Wh1, Wh2, Htot);
    row_kernel<<<NN / 4, 256, 0, stream>>>(Hb, Wh1, Wh2, Htot, cnt, csr_col, bias, out);
}